// Round 1
// baseline (5806.478 us; speedup 1.0000x reference)
//
#include <hip/hip_runtime.h>

// ---------------- kernels ----------------

__global__ void deg_init_k(float* __restrict__ deg, int n) {
    int i = blockIdx.x * 256 + threadIdx.x;
    if (i < n) deg[i] = 1.0f;  // self-loop counts once
}

__global__ void deg_count_k(const int* __restrict__ dst, float* __restrict__ deg, int E) {
    int e = blockIdx.x * 256 + threadIdx.x;
    if (e < E) atomicAdd(&deg[dst[e]], 1.0f);
}

__global__ void rsqrt_k(float* __restrict__ d, int n) {
    int i = blockIdx.x * 256 + threadIdx.x;
    if (i < n) d[i] = rsqrtf(d[i]);  // deg >= 1 always (self-loop)
}

__global__ void norm_k(const int* __restrict__ src, const int* __restrict__ dst,
                       const float* __restrict__ dinv, float* __restrict__ norm, int E) {
    int e = blockIdx.x * 256 + threadIdx.x;
    if (e < E) norm[e] = dinv[src[e]] * dinv[dst[e]];
}

// H = X @ W ; W is 128x128 staged in LDS (64KB). 32 rows per block, 256 threads.
// Thread (c4 = tid&31, rg = tid>>5) computes rows {rg, rg+8, rg+16, rg+24} x cols [4*c4..4*c4+3].
__global__ void gemm_k(const float* __restrict__ X, const float* __restrict__ W,
                       float* __restrict__ H, int N) {
    __shared__ float wsh[128 * 128];
    int tid = threadIdx.x;
    const float4* W4 = (const float4*)W;
    float4* ws4 = (float4*)wsh;
#pragma unroll
    for (int i = 0; i < 16; ++i) ws4[tid + 256 * i] = W4[tid + 256 * i];
    __syncthreads();

    int row0 = blockIdx.x * 32;
    int c4 = tid & 31;
    int rg = tid >> 5;

    int rows[4];
    bool ok[4];
#pragma unroll
    for (int rr = 0; rr < 4; ++rr) {
        rows[rr] = row0 + rg + 8 * rr;
        ok[rr] = rows[rr] < N;
    }

    float acc[4][4] = {};
    const float4* X4 = (const float4*)X;

    for (int kk = 0; kk < 32; ++kk) {
        float xr[4][4];
#pragma unroll
        for (int rr = 0; rr < 4; ++rr) {
            float4 xv = ok[rr] ? X4[(size_t)rows[rr] * 32 + kk] : make_float4(0.f, 0.f, 0.f, 0.f);
            xr[rr][0] = xv.x; xr[rr][1] = xv.y; xr[rr][2] = xv.z; xr[rr][3] = xv.w;
        }
#pragma unroll
        for (int j = 0; j < 4; ++j) {
            int k = kk * 4 + j;
            float4 w = ws4[k * 32 + c4];
#pragma unroll
            for (int rr = 0; rr < 4; ++rr) {
                acc[rr][0] = fmaf(xr[rr][j], w.x, acc[rr][0]);
                acc[rr][1] = fmaf(xr[rr][j], w.y, acc[rr][1]);
                acc[rr][2] = fmaf(xr[rr][j], w.z, acc[rr][2]);
                acc[rr][3] = fmaf(xr[rr][j], w.w, acc[rr][3]);
            }
        }
    }

#pragma unroll
    for (int rr = 0; rr < 4; ++rr) {
        if (ok[rr]) {
            float4 o;
            o.x = acc[rr][0]; o.y = acc[rr][1]; o.z = acc[rr][2]; o.w = acc[rr][3];
            ((float4*)(H + (size_t)rows[rr] * 128))[c4] = o;
        }
    }
}

// agg[i][:] = b + H[i][:] * dinv[i]^2   (bias + self-loop term), float4 over N*32
__global__ void agg_init_k(const float* __restrict__ H, const float* __restrict__ dinv,
                           const float* __restrict__ b, float* __restrict__ out, int N) {
    int idx = blockIdx.x * 256 + threadIdx.x;
    if (idx >= N * 32) return;
    int i = idx >> 5;
    int c4 = idx & 31;
    float dn = dinv[i];
    float sn = dn * dn;
    float4 h = ((const float4*)H)[idx];
    float4 bb = ((const float4*)b)[c4];
    float4 o;
    o.x = fmaf(h.x, sn, bb.x);
    o.y = fmaf(h.y, sn, bb.y);
    o.z = fmaf(h.z, sn, bb.z);
    o.w = fmaf(h.w, sn, bb.w);
    ((float4*)out)[idx] = o;
}

// 32 threads per edge: gather h[src] (float4/lane), scale by norm, atomic scatter into out[dst]
__global__ void edge_agg_k(const float* __restrict__ H, const int* __restrict__ src,
                           const int* __restrict__ dst, const float* __restrict__ norm,
                           float* __restrict__ out, int E) {
    int t = blockIdx.x * 256 + threadIdx.x;
    int eid = t >> 5;
    if (eid >= E) return;
    int lane = t & 31;
    int s = src[eid];
    int d = dst[eid];
    float nr = norm[eid];
    float4 v = ((const float4*)(H + (size_t)s * 128))[lane];
    float* o = out + (size_t)d * 128 + lane * 4;
    atomicAdd(o + 0, v.x * nr);
    atomicAdd(o + 1, v.y * nr);
    atomicAdd(o + 2, v.z * nr);
    atomicAdd(o + 3, v.w * nr);
}

__global__ void relu_k(float* __restrict__ x, int n4) {
    int idx = blockIdx.x * 256 + threadIdx.x;
    if (idx >= n4) return;
    float4 v = ((float4*)x)[idx];
    v.x = fmaxf(v.x, 0.f);
    v.y = fmaxf(v.y, 0.f);
    v.z = fmaxf(v.z, 0.f);
    v.w = fmaxf(v.w, 0.f);
    ((float4*)x)[idx] = v;
}

// ---------------- launch ----------------

extern "C" void kernel_launch(void* const* d_in, const int* in_sizes, int n_in,
                              void* d_out, int out_size, void* d_ws, size_t ws_size,
                              hipStream_t stream) {
    const float* x = (const float*)d_in[0];
    const int* ei = (const int*)d_in[1];
    const int E = in_sizes[1] / 2;
    const int* srcI = ei;
    const int* dstI = ei + E;
    const float* W[4] = {(const float*)d_in[2], (const float*)d_in[4],
                         (const float*)d_in[6], (const float*)d_in[8]};
    const float* b[4] = {(const float*)d_in[3], (const float*)d_in[5],
                         (const float*)d_in[7], (const float*)d_in[9]};
    const int N = in_sizes[0] / 128;

    float* ws = (float*)d_ws;
    float* dinv = ws;                       // N floats (pad to 50176)
    float* normv = ws + 50176;              // E floats
    float* bufA = normv + ((E + 15) & ~15); // N*128 (h)
    float* bufB = bufA + (size_t)N * 128;   // N*128 (agg)

    dim3 blk(256);
    int gN = (N + 255) / 256;
    int gE = (E + 255) / 256;
    int gF = (N * 32 + 255) / 256;          // N*128/4 float4 elements
    int gEdge = (int)(((size_t)E * 32 + 255) / 256);
    int gGemm = (N + 31) / 32;

    deg_init_k<<<gN, blk, 0, stream>>>(dinv, N);
    deg_count_k<<<gE, blk, 0, stream>>>(dstI, dinv, E);
    rsqrt_k<<<gN, blk, 0, stream>>>(dinv, N);
    norm_k<<<gE, blk, 0, stream>>>(srcI, dstI, dinv, normv, E);

    const float* in = x;
    for (int l = 0; l < 4; ++l) {
        gemm_k<<<gGemm, blk, 0, stream>>>(in, W[l], bufA, N);
        float* agg = (l == 3) ? (float*)d_out : bufB;
        agg_init_k<<<gF, blk, 0, stream>>>(bufA, dinv, b[l], agg, N);
        edge_agg_k<<<gEdge, blk, 0, stream>>>(bufA, srcI, dstI, normv, agg, E);
        relu_k<<<gF, blk, 0, stream>>>(agg, N * 32);
        in = agg;
    }
}

// Round 2
// 770.512 us; speedup vs baseline: 7.5359x; 7.5359x over previous
//
#include <hip/hip_runtime.h>

// ---------------- setup kernels (once per call) ----------------

// cnt = 0, cursor = 0
__global__ void init_k(int* __restrict__ cnt, int* __restrict__ cursor, int n) {
    int i = blockIdx.x * 256 + threadIdx.x;
    if (i < n) { cnt[i] = 0; cursor[i] = 0; }
}

// histogram of incoming-edge counts (excluding self-loop)
__global__ void hist_k(const int* __restrict__ dst, int* __restrict__ cnt, int E) {
    int e = blockIdx.x * 256 + threadIdx.x;
    if (e < E) atomicAdd(&cnt[dst[e]], 1);
}

// dinv[i] = rsqrt(cnt[i] + 1)   (self-loop adds 1 to degree)
__global__ void dinv_k(const int* __restrict__ cnt, float* __restrict__ dinv, int n) {
    int i = blockIdx.x * 256 + threadIdx.x;
    if (i < n) dinv[i] = rsqrtf((float)cnt[i] + 1.0f);
}

// single-block exclusive scan: rowptr[0]=0, rowptr[i+1]=sum(cnt[0..i])
__global__ void scan_k(const int* __restrict__ cnt, int* __restrict__ rowptr, int n) {
    __shared__ int sh[1024];
    __shared__ int carry;
    int tid = threadIdx.x;
    if (tid == 0) { carry = 0; rowptr[0] = 0; }
    __syncthreads();
    for (int base = 0; base < n; base += 1024) {
        int i = base + tid;
        int v = (i < n) ? cnt[i] : 0;
        sh[tid] = v;
        __syncthreads();
#pragma unroll
        for (int off = 1; off < 1024; off <<= 1) {
            int t = (tid >= off) ? sh[tid - off] : 0;
            __syncthreads();
            sh[tid] += t;
            __syncthreads();
        }
        if (i < n) rowptr[i + 1] = carry + sh[tid];
        __syncthreads();
        if (tid == 1023) carry += sh[1023];
        __syncthreads();
    }
}

// scatter edge (src, weight) into CSR slots grouped by dst
__global__ void fill_k(const int* __restrict__ src, const int* __restrict__ dst,
                       const float* __restrict__ dinv, const int* __restrict__ rowptr,
                       int* __restrict__ cursor, int2* __restrict__ edata, int E) {
    int e = blockIdx.x * 256 + threadIdx.x;
    if (e >= E) return;
    int d = dst[e];
    int s = src[e];
    int pos = rowptr[d] + atomicAdd(&cursor[d], 1);
    float w = dinv[s] * dinv[d];
    edata[pos] = make_int2(s, __float_as_int(w));
}

// ---------------- per-layer kernels ----------------

// H = X @ W ; W is 128x128 staged in LDS (64KB). 32 rows per block, 256 threads.
__global__ void gemm_k(const float* __restrict__ X, const float* __restrict__ W,
                       float* __restrict__ H, int N) {
    __shared__ float wsh[128 * 128];
    int tid = threadIdx.x;
    const float4* W4 = (const float4*)W;
    float4* ws4 = (float4*)wsh;
#pragma unroll
    for (int i = 0; i < 16; ++i) ws4[tid + 256 * i] = W4[tid + 256 * i];
    __syncthreads();

    int row0 = blockIdx.x * 32;
    int c4 = tid & 31;
    int rg = tid >> 5;

    int rows[4];
    bool ok[4];
#pragma unroll
    for (int rr = 0; rr < 4; ++rr) {
        rows[rr] = row0 + rg + 8 * rr;
        ok[rr] = rows[rr] < N;
    }

    float acc[4][4] = {};
    const float4* X4 = (const float4*)X;

    for (int kk = 0; kk < 32; ++kk) {
        float xr[4][4];
#pragma unroll
        for (int rr = 0; rr < 4; ++rr) {
            float4 xv = ok[rr] ? X4[(size_t)rows[rr] * 32 + kk] : make_float4(0.f, 0.f, 0.f, 0.f);
            xr[rr][0] = xv.x; xr[rr][1] = xv.y; xr[rr][2] = xv.z; xr[rr][3] = xv.w;
        }
#pragma unroll
        for (int j = 0; j < 4; ++j) {
            int k = kk * 4 + j;
            float4 w = ws4[k * 32 + c4];
#pragma unroll
            for (int rr = 0; rr < 4; ++rr) {
                acc[rr][0] = fmaf(xr[rr][j], w.x, acc[rr][0]);
                acc[rr][1] = fmaf(xr[rr][j], w.y, acc[rr][1]);
                acc[rr][2] = fmaf(xr[rr][j], w.z, acc[rr][2]);
                acc[rr][3] = fmaf(xr[rr][j], w.w, acc[rr][3]);
            }
        }
    }

#pragma unroll
    for (int rr = 0; rr < 4; ++rr) {
        if (ok[rr]) {
            float4 o;
            o.x = acc[rr][0]; o.y = acc[rr][1]; o.z = acc[rr][2]; o.w = acc[rr][3];
            ((float4*)(H + (size_t)rows[rr] * 128))[c4] = o;
        }
    }
}

// Gather-aggregate: out[i] = relu(b + dinv[i]^2 * H[i] + sum_{e: dst=i} w_e * H[src_e])
// 32 lanes per node, float4 per lane (128 features).
__global__ void gather_agg_k(const float* __restrict__ H, const int* __restrict__ rowptr,
                             const int2* __restrict__ edata, const float* __restrict__ dinv,
                             const float* __restrict__ b, float* __restrict__ out, int N) {
    int t = blockIdx.x * 256 + threadIdx.x;
    int i = t >> 5;
    if (i >= N) return;
    int lane = t & 31;

    float dn = dinv[i];
    float sn = dn * dn;
    float4 bb = ((const float4*)b)[lane];
    float4 hi = ((const float4*)(H + (size_t)i * 128))[lane];
    float4 acc;
    acc.x = fmaf(hi.x, sn, bb.x);
    acc.y = fmaf(hi.y, sn, bb.y);
    acc.z = fmaf(hi.z, sn, bb.z);
    acc.w = fmaf(hi.w, sn, bb.w);

    int p0 = rowptr[i];
    int p1 = rowptr[i + 1];
    for (int p = p0; p < p1; ++p) {
        int2 ed = edata[p];
        int s = ed.x;
        float w = __int_as_float(ed.y);
        float4 v = ((const float4*)(H + (size_t)s * 128))[lane];
        acc.x = fmaf(v.x, w, acc.x);
        acc.y = fmaf(v.y, w, acc.y);
        acc.z = fmaf(v.z, w, acc.z);
        acc.w = fmaf(v.w, w, acc.w);
    }

    acc.x = fmaxf(acc.x, 0.f);
    acc.y = fmaxf(acc.y, 0.f);
    acc.z = fmaxf(acc.z, 0.f);
    acc.w = fmaxf(acc.w, 0.f);
    ((float4*)(out + (size_t)i * 128))[lane] = acc;
}

// ---------------- launch ----------------

extern "C" void kernel_launch(void* const* d_in, const int* in_sizes, int n_in,
                              void* d_out, int out_size, void* d_ws, size_t ws_size,
                              hipStream_t stream) {
    const float* x = (const float*)d_in[0];
    const int* ei = (const int*)d_in[1];
    const int E = in_sizes[1] / 2;
    const int* srcI = ei;
    const int* dstI = ei + E;
    const float* W[4] = {(const float*)d_in[2], (const float*)d_in[4],
                         (const float*)d_in[6], (const float*)d_in[8]};
    const float* b[4] = {(const float*)d_in[3], (const float*)d_in[5],
                         (const float*)d_in[7], (const float*)d_in[9]};
    const int N = in_sizes[0] / 128;

    // ws layout (4B units); 50176 = 16-aligned pad over N=50000
    int* iws = (int*)d_ws;
    int* cnt = iws;                           // [0, 50176)
    int* rowptr = iws + 50176;                // [50176, 100352)  (N+1 used)
    int* cursor = iws + 100352;               // [100352, 150528)
    float* dinv = (float*)(iws + 150528);     // [150528, 200704)
    int2* edata = (int2*)(iws + 200704);      // 2*E ints
    float* bufA = (float*)(iws + 200704 + 2 * E);            // N*128
    float* bufB = bufA + (size_t)N * 128;                    // N*128

    dim3 blk(256);
    int gN = (N + 255) / 256;
    int gE = (E + 255) / 256;
    int gGemm = (N + 31) / 32;
    int gGather = (N * 32 + 255) / 256;

    init_k<<<gN, blk, 0, stream>>>(cnt, cursor, N);
    hist_k<<<gE, blk, 0, stream>>>(dstI, cnt, E);
    dinv_k<<<gN, blk, 0, stream>>>(cnt, dinv, N);
    scan_k<<<1, 1024, 0, stream>>>(cnt, rowptr, N);
    fill_k<<<gE, blk, 0, stream>>>(srcI, dstI, dinv, rowptr, cursor, edata, E);

    const float* in = x;
    for (int l = 0; l < 4; ++l) {
        gemm_k<<<gGemm, blk, 0, stream>>>(in, W[l], bufA, N);
        float* agg = (l == 3) ? (float*)d_out : bufB;
        gather_agg_k<<<gGather, blk, 0, stream>>>(bufA, rowptr, edata, dinv, b[l], agg, N);
        in = agg;
    }
}

// Round 3
// 476.101 us; speedup vs baseline: 12.1959x; 1.6184x over previous
//
#include <hip/hip_runtime.h>

// ---------------- setup kernels (once per call) ----------------

__global__ void init_k(int* __restrict__ cnt, int* __restrict__ cursor, int n) {
    int i = blockIdx.x * 256 + threadIdx.x;
    if (i < n) { cnt[i] = 0; cursor[i] = 0; }
}

__global__ void hist_k(const int* __restrict__ dst, int* __restrict__ cnt, int E) {
    int e = blockIdx.x * 256 + threadIdx.x;
    if (e < E) atomicAdd(&cnt[dst[e]], 1);
}

__global__ void dinv_k(const int* __restrict__ cnt, float* __restrict__ dinv, int n) {
    int i = blockIdx.x * 256 + threadIdx.x;
    if (i < n) dinv[i] = rsqrtf((float)cnt[i] + 1.0f);
}

// --- hierarchical exclusive scan of cnt[0..n) -> rowptr[0..n], 1024 elems/block ---

__global__ void bsum_k(const int* __restrict__ cnt, int* __restrict__ bsum, int n) {
    int b = blockIdx.x, tid = threadIdx.x;
    int base = b * 1024 + tid * 4;
    int4 v = make_int4(0, 0, 0, 0);
    if (base + 3 < n) v = *(const int4*)(cnt + base);
    else {
        if (base + 0 < n) v.x = cnt[base + 0];
        if (base + 1 < n) v.y = cnt[base + 1];
        if (base + 2 < n) v.z = cnt[base + 2];
    }
    int s = v.x + v.y + v.z + v.w;
#pragma unroll
    for (int off = 32; off; off >>= 1) s += __shfl_xor(s, off, 64);
    __shared__ int wsh[4];
    if ((tid & 63) == 0) wsh[tid >> 6] = s;
    __syncthreads();
    if (tid == 0) bsum[b] = wsh[0] + wsh[1] + wsh[2] + wsh[3];
}

__global__ void bscan_k(const int* __restrict__ bsum, int* __restrict__ boffs, int nb) {
    int tid = threadIdx.x;
    int lane = tid & 63, wid = tid >> 6;
    int s = (tid < nb) ? bsum[tid] : 0;
    int incl = s;
#pragma unroll
    for (int off = 1; off < 64; off <<= 1) {
        int t = __shfl_up(incl, off, 64);
        if (lane >= off) incl += t;
    }
    __shared__ int wsh[4];
    if (lane == 63) wsh[wid] = incl;
    __syncthreads();
    int woff = 0;
    for (int w = 0; w < wid; ++w) woff += wsh[w];
    if (tid < nb) boffs[tid] = woff + incl - s;  // exclusive
}

__global__ void rowscan_k(const int* __restrict__ cnt, const int* __restrict__ boffs,
                          int* __restrict__ rowptr, int n) {
    int b = blockIdx.x, tid = threadIdx.x;
    int lane = tid & 63, wid = tid >> 6;
    int base = b * 1024 + tid * 4;
    int4 v = make_int4(0, 0, 0, 0);
    if (base + 3 < n) v = *(const int4*)(cnt + base);
    else {
        if (base + 0 < n) v.x = cnt[base + 0];
        if (base + 1 < n) v.y = cnt[base + 1];
        if (base + 2 < n) v.z = cnt[base + 2];
    }
    int s = v.x + v.y + v.z + v.w;
    int incl = s;
#pragma unroll
    for (int off = 1; off < 64; off <<= 1) {
        int t = __shfl_up(incl, off, 64);
        if (lane >= off) incl += t;
    }
    __shared__ int wsh[4];
    if (lane == 63) wsh[wid] = incl;
    __syncthreads();
    int woff = boffs[b];
    for (int w = 0; w < wid; ++w) woff += wsh[w];
    int e0 = woff + incl - s;
    int o0 = e0 + v.x, o1 = o0 + v.y, o2 = o1 + v.z, o3 = o2 + v.w;
    if (base + 0 < n) rowptr[base + 1] = o0;
    if (base + 1 < n) rowptr[base + 2] = o1;
    if (base + 2 < n) rowptr[base + 3] = o2;
    if (base + 3 < n) rowptr[base + 4] = o3;
    if (b == 0 && tid == 0) rowptr[0] = 0;
}

__global__ void fill_k(const int* __restrict__ src, const int* __restrict__ dst,
                       const float* __restrict__ dinv, const int* __restrict__ rowptr,
                       int* __restrict__ cursor, int2* __restrict__ edata, int E) {
    int e = blockIdx.x * 256 + threadIdx.x;
    if (e >= E) return;
    int d = dst[e];
    int s = src[e];
    int pos = rowptr[d] + atomicAdd(&cursor[d], 1);
    float w = dinv[s] * dinv[d];
    edata[pos] = make_int2(s, __float_as_int(w));
}

// ---------------- per-layer kernels ----------------

// H = X @ W. 64 X-rows staged in 32KB LDS; W (64KB) read from global (L1/L2-hot).
// 256 threads: thread (c4 = tid&31, rg = tid>>5) computes rows rg+8*rr (rr=0..7),
// cols [4*c4 .. 4*c4+3].
__global__ __launch_bounds__(256, 4) void gemm_k(const float* __restrict__ X,
                                                 const float* __restrict__ W,
                                                 float* __restrict__ H, int N) {
    __shared__ float4 xs[64 * 32];  // 32 KB
    int tid = threadIdx.x;
    int row0 = blockIdx.x * 64;
    int nrows = min(64, N - row0);
    const float4* X4 = (const float4*)X;
#pragma unroll
    for (int i = 0; i < 8; ++i) {
        int idx = i * 256 + tid;
        int r = idx >> 5;
        xs[idx] = (r < nrows) ? X4[(size_t)row0 * 32 + idx] : make_float4(0.f, 0.f, 0.f, 0.f);
    }
    __syncthreads();

    int c4 = tid & 31;
    int rg = tid >> 5;
    float acc[8][4] = {};
    const float4* W4 = (const float4*)W;

    for (int kk = 0; kk < 32; ++kk) {
        float4 w[4];
#pragma unroll
        for (int j = 0; j < 4; ++j) w[j] = W4[(kk * 4 + j) * 32 + c4];
#pragma unroll
        for (int rr = 0; rr < 8; ++rr) {
            float4 xv = xs[(rg + 8 * rr) * 32 + kk];
#pragma unroll
            for (int c = 0; c < 4; ++c) {
                float* a = &acc[rr][c];
                float wc0 = (&w[0].x)[c];
                float wc1 = (&w[1].x)[c];
                float wc2 = (&w[2].x)[c];
                float wc3 = (&w[3].x)[c];
                *a = fmaf(xv.x, wc0, *a);
                *a = fmaf(xv.y, wc1, *a);
                *a = fmaf(xv.z, wc2, *a);
                *a = fmaf(xv.w, wc3, *a);
            }
        }
    }

#pragma unroll
    for (int rr = 0; rr < 8; ++rr) {
        int r = rg + 8 * rr;
        if (r < nrows) {
            float4 o;
            o.x = acc[rr][0]; o.y = acc[rr][1]; o.z = acc[rr][2]; o.w = acc[rr][3];
            ((float4*)(H + (size_t)(row0 + r) * 128))[c4] = o;
        }
    }
}

// out[i] = relu(b + dinv[i]^2 * H[i] + sum_{e: dst=i} w_e * H[src_e])
__global__ void gather_agg_k(const float* __restrict__ H, const int* __restrict__ rowptr,
                             const int2* __restrict__ edata, const float* __restrict__ dinv,
                             const float* __restrict__ b, float* __restrict__ out, int N) {
    int t = blockIdx.x * 256 + threadIdx.x;
    int i = t >> 5;
    if (i >= N) return;
    int lane = t & 31;

    float dn = dinv[i];
    float sn = dn * dn;
    float4 bb = ((const float4*)b)[lane];
    float4 hi = ((const float4*)(H + (size_t)i * 128))[lane];
    float4 acc;
    acc.x = fmaf(hi.x, sn, bb.x);
    acc.y = fmaf(hi.y, sn, bb.y);
    acc.z = fmaf(hi.z, sn, bb.z);
    acc.w = fmaf(hi.w, sn, bb.w);

    int p0 = rowptr[i];
    int p1 = rowptr[i + 1];
    if (p0 < p1) {
        int2 ed = edata[p0];
        int p = p0;
        while (true) {
            int2 nxt;
            bool more = (p + 1 < p1);
            if (more) nxt = edata[p + 1];
            float w = __int_as_float(ed.y);
            float4 v = ((const float4*)(H + (size_t)ed.x * 128))[lane];
            acc.x = fmaf(v.x, w, acc.x);
            acc.y = fmaf(v.y, w, acc.y);
            acc.z = fmaf(v.z, w, acc.z);
            acc.w = fmaf(v.w, w, acc.w);
            if (!more) break;
            ed = nxt;
            ++p;
        }
    }

    acc.x = fmaxf(acc.x, 0.f);
    acc.y = fmaxf(acc.y, 0.f);
    acc.z = fmaxf(acc.z, 0.f);
    acc.w = fmaxf(acc.w, 0.f);
    ((float4*)(out + (size_t)i * 128))[lane] = acc;
}

// ---------------- launch ----------------

extern "C" void kernel_launch(void* const* d_in, const int* in_sizes, int n_in,
                              void* d_out, int out_size, void* d_ws, size_t ws_size,
                              hipStream_t stream) {
    const float* x = (const float*)d_in[0];
    const int* ei = (const int*)d_in[1];
    const int E = in_sizes[1] / 2;
    const int* srcI = ei;
    const int* dstI = ei + E;
    const float* W[4] = {(const float*)d_in[2], (const float*)d_in[4],
                         (const float*)d_in[6], (const float*)d_in[8]};
    const float* b[4] = {(const float*)d_in[3], (const float*)d_in[5],
                         (const float*)d_in[7], (const float*)d_in[9]};
    const int N = in_sizes[0] / 128;

    // ws layout (4B units)
    int* iws = (int*)d_ws;
    int* cnt = iws;                           // [0, 50176)
    int* rowptr = iws + 50176;                // [50176, 100352)
    int* cursor = iws + 100352;               // [100352, 150528)
    float* dinv = (float*)(iws + 150528);     // [150528, 200704)
    int* bsum = iws + 200704;                 // 64
    int* boffs = iws + 200768;                // 64
    int2* edata = (int2*)(iws + 200832);      // 2*E ints
    float* bufA = (float*)(iws + 200832 + 2 * E);
    float* bufB = bufA + (size_t)N * 128;

    dim3 blk(256);
    int gN = (N + 255) / 256;
    int gE = (E + 255) / 256;
    int NB = (N + 1023) / 1024;
    int gGemm = (N + 63) / 64;
    int gGather = (N * 32 + 255) / 256;

    init_k<<<gN, blk, 0, stream>>>(cnt, cursor, N);
    hist_k<<<gE, blk, 0, stream>>>(dstI, cnt, E);
    dinv_k<<<gN, blk, 0, stream>>>(cnt, dinv, N);
    bsum_k<<<NB, blk, 0, stream>>>(cnt, bsum, N);
    bscan_k<<<1, blk, 0, stream>>>(bsum, boffs, NB);
    rowscan_k<<<NB, blk, 0, stream>>>(cnt, boffs, rowptr, N);
    fill_k<<<gE, blk, 0, stream>>>(srcI, dstI, dinv, rowptr, cursor, edata, E);

    const float* in = x;
    for (int l = 0; l < 4; ++l) {
        gemm_k<<<gGemm, blk, 0, stream>>>(in, W[l], bufA, N);
        float* agg = (l == 3) ? (float*)d_out : bufB;
        gather_agg_k<<<gGather, blk, 0, stream>>>(bufA, rowptr, edata, dinv, b[l], agg, N);
        in = agg;
    }
}

// Round 4
// 439.141 us; speedup vs baseline: 13.2223x; 1.0842x over previous
//
#include <hip/hip_runtime.h>

// ---------------- setup kernels (once per call) ----------------

__global__ void hist_k(const int* __restrict__ dst, int* __restrict__ cnt, int E) {
    int e = blockIdx.x * 256 + threadIdx.x;
    if (e < E) atomicAdd(&cnt[dst[e]], 1);
}

// per-block sums of cnt (1024/block) + fused dinv = rsqrt(cnt+1)
__global__ void bsum_k(const int* __restrict__ cnt, int* __restrict__ bsum,
                       float* __restrict__ dinv, int n) {
    int b = blockIdx.x, tid = threadIdx.x;
    int base = b * 1024 + tid * 4;
    int4 v = make_int4(0, 0, 0, 0);
    if (base + 3 < n) v = *(const int4*)(cnt + base);
    else {
        if (base + 0 < n) v.x = cnt[base + 0];
        if (base + 1 < n) v.y = cnt[base + 1];
        if (base + 2 < n) v.z = cnt[base + 2];
    }
    if (base + 3 < n) {
        float4 dv;
        dv.x = rsqrtf((float)v.x + 1.0f);
        dv.y = rsqrtf((float)v.y + 1.0f);
        dv.z = rsqrtf((float)v.z + 1.0f);
        dv.w = rsqrtf((float)v.w + 1.0f);
        *(float4*)(dinv + base) = dv;
    } else {
        if (base + 0 < n) dinv[base + 0] = rsqrtf((float)v.x + 1.0f);
        if (base + 1 < n) dinv[base + 1] = rsqrtf((float)v.y + 1.0f);
        if (base + 2 < n) dinv[base + 2] = rsqrtf((float)v.z + 1.0f);
    }
    int s = v.x + v.y + v.z + v.w;
#pragma unroll
    for (int off = 32; off; off >>= 1) s += __shfl_xor(s, off, 64);
    __shared__ int wsh[4];
    if ((tid & 63) == 0) wsh[tid >> 6] = s;
    __syncthreads();
    if (tid == 0) bsum[b] = wsh[0] + wsh[1] + wsh[2] + wsh[3];
}

__global__ void bscan_k(const int* __restrict__ bsum, int* __restrict__ boffs, int nb) {
    int tid = threadIdx.x;
    int lane = tid & 63, wid = tid >> 6;
    int s = (tid < nb) ? bsum[tid] : 0;
    int incl = s;
#pragma unroll
    for (int off = 1; off < 64; off <<= 1) {
        int t = __shfl_up(incl, off, 64);
        if (lane >= off) incl += t;
    }
    __shared__ int wsh[4];
    if (lane == 63) wsh[wid] = incl;
    __syncthreads();
    int woff = 0;
    for (int w = 0; w < wid; ++w) woff += wsh[w];
    if (tid < nb) boffs[tid] = woff + incl - s;  // exclusive
}

__global__ void rowscan_k(const int* __restrict__ cnt, const int* __restrict__ boffs,
                          int* __restrict__ rowptr, int n) {
    int b = blockIdx.x, tid = threadIdx.x;
    int lane = tid & 63, wid = tid >> 6;
    int base = b * 1024 + tid * 4;
    int4 v = make_int4(0, 0, 0, 0);
    if (base + 3 < n) v = *(const int4*)(cnt + base);
    else {
        if (base + 0 < n) v.x = cnt[base + 0];
        if (base + 1 < n) v.y = cnt[base + 1];
        if (base + 2 < n) v.z = cnt[base + 2];
    }
    int s = v.x + v.y + v.z + v.w;
    int incl = s;
#pragma unroll
    for (int off = 1; off < 64; off <<= 1) {
        int t = __shfl_up(incl, off, 64);
        if (lane >= off) incl += t;
    }
    __shared__ int wsh[4];
    if (lane == 63) wsh[wid] = incl;
    __syncthreads();
    int woff = boffs[b];
    for (int w = 0; w < wid; ++w) woff += wsh[w];
    int e0 = woff + incl - s;
    int o0 = e0 + v.x, o1 = o0 + v.y, o2 = o1 + v.z, o3 = o2 + v.w;
    if (base + 0 < n) rowptr[base + 1] = o0;
    if (base + 1 < n) rowptr[base + 2] = o1;
    if (base + 2 < n) rowptr[base + 3] = o2;
    if (base + 3 < n) rowptr[base + 4] = o3;
    if (b == 0 && tid == 0) rowptr[0] = 0;
}

__global__ void fill_k(const int* __restrict__ src, const int* __restrict__ dst,
                       const float* __restrict__ dinv, const int* __restrict__ rowptr,
                       int* __restrict__ cursor, int2* __restrict__ edata, int E) {
    int e = blockIdx.x * 256 + threadIdx.x;
    if (e >= E) return;
    int d = dst[e];
    int s = src[e];
    int pos = rowptr[d] + atomicAdd(&cursor[d], 1);
    float w = dinv[s] * dinv[d];
    edata[pos] = make_int2(s, __float_as_int(w));
}

// ---------------- per-layer kernels ----------------

// H = X @ W. 64 X-rows staged in 32KB LDS; W read from global (L1/L2-hot) with
// one-quad software pipeline.
__global__ __launch_bounds__(256, 4) void gemm_k(const float* __restrict__ X,
                                                 const float* __restrict__ W,
                                                 float* __restrict__ H, int N) {
    __shared__ float4 xs[64 * 32];  // 32 KB
    int tid = threadIdx.x;
    int row0 = blockIdx.x * 64;
    int nrows = min(64, N - row0);
    const float4* X4 = (const float4*)X;
#pragma unroll
    for (int i = 0; i < 8; ++i) {
        int idx = i * 256 + tid;
        int r = idx >> 5;
        xs[idx] = (r < nrows) ? X4[(size_t)row0 * 32 + idx] : make_float4(0.f, 0.f, 0.f, 0.f);
    }
    __syncthreads();

    int c4 = tid & 31;
    int rg = tid >> 5;
    float acc[8][4] = {};
    const float4* W4 = (const float4*)W;

    float4 w[4];
#pragma unroll
    for (int j = 0; j < 4; ++j) w[j] = W4[j * 32 + c4];

    for (int kk = 0; kk < 32; ++kk) {
        float4 wn[4];
        int kn = (kk + 1) & 31;  // wraps on last iter (harmless extra load of row 0..3)
#pragma unroll
        for (int j = 0; j < 4; ++j) wn[j] = W4[(kn * 4 + j) * 32 + c4];
#pragma unroll
        for (int rr = 0; rr < 8; ++rr) {
            float4 xv = xs[(rg + 8 * rr) * 32 + kk];
#pragma unroll
            for (int c = 0; c < 4; ++c) {
                float* a = &acc[rr][c];
                *a = fmaf(xv.x, (&w[0].x)[c], *a);
                *a = fmaf(xv.y, (&w[1].x)[c], *a);
                *a = fmaf(xv.z, (&w[2].x)[c], *a);
                *a = fmaf(xv.w, (&w[3].x)[c], *a);
            }
        }
#pragma unroll
        for (int j = 0; j < 4; ++j) w[j] = wn[j];
    }

#pragma unroll
    for (int rr = 0; rr < 8; ++rr) {
        int r = rg + 8 * rr;
        if (r < nrows) {
            float4 o;
            o.x = acc[rr][0]; o.y = acc[rr][1]; o.z = acc[rr][2]; o.w = acc[rr][3];
            ((float4*)(H + (size_t)(row0 + r) * 128))[c4] = o;
        }
    }
}

// out[i] = relu(b + dinv[i]^2 * H[i] + sum_{e: dst=i} w_e * H[src_e])
// 32 lanes/node, 4 edges in flight (4-deep MLP).
__global__ __launch_bounds__(256) void gather_agg_k(
        const float* __restrict__ H, const int* __restrict__ rowptr,
        const int2* __restrict__ edata, const float* __restrict__ dinv,
        const float* __restrict__ b, float* __restrict__ out, int N) {
    int t = blockIdx.x * 256 + threadIdx.x;
    int i = t >> 5;
    if (i >= N) return;
    int lane = t & 31;
    const float4* H4 = (const float4*)H;

    float dn = dinv[i];
    float sn = dn * dn;
    float4 bb = ((const float4*)b)[lane];
    float4 hi = H4[(size_t)i * 32 + lane];
    float4 a0, a1;
    a0.x = fmaf(hi.x, sn, bb.x);
    a0.y = fmaf(hi.y, sn, bb.y);
    a0.z = fmaf(hi.z, sn, bb.z);
    a0.w = fmaf(hi.w, sn, bb.w);
    a1 = make_float4(0.f, 0.f, 0.f, 0.f);

    int p0 = rowptr[i];
    int p1 = rowptr[i + 1];
    int p = p0;
    for (; p + 4 <= p1; p += 4) {
        int2 e0 = edata[p + 0];
        int2 e1 = edata[p + 1];
        int2 e2 = edata[p + 2];
        int2 e3 = edata[p + 3];
        float4 v0 = H4[(size_t)e0.x * 32 + lane];
        float4 v1 = H4[(size_t)e1.x * 32 + lane];
        float4 v2 = H4[(size_t)e2.x * 32 + lane];
        float4 v3 = H4[(size_t)e3.x * 32 + lane];
        float w0 = __int_as_float(e0.y);
        float w1 = __int_as_float(e1.y);
        float w2 = __int_as_float(e2.y);
        float w3 = __int_as_float(e3.y);
        a0.x = fmaf(v0.x, w0, a0.x); a0.y = fmaf(v0.y, w0, a0.y);
        a0.z = fmaf(v0.z, w0, a0.z); a0.w = fmaf(v0.w, w0, a0.w);
        a1.x = fmaf(v1.x, w1, a1.x); a1.y = fmaf(v1.y, w1, a1.y);
        a1.z = fmaf(v1.z, w1, a1.z); a1.w = fmaf(v1.w, w1, a1.w);
        a0.x = fmaf(v2.x, w2, a0.x); a0.y = fmaf(v2.y, w2, a0.y);
        a0.z = fmaf(v2.z, w2, a0.z); a0.w = fmaf(v2.w, w2, a0.w);
        a1.x = fmaf(v3.x, w3, a1.x); a1.y = fmaf(v3.y, w3, a1.y);
        a1.z = fmaf(v3.z, w3, a1.z); a1.w = fmaf(v3.w, w3, a1.w);
    }
    for (; p < p1; ++p) {
        int2 e = edata[p];
        float w = __int_as_float(e.y);
        float4 v = H4[(size_t)e.x * 32 + lane];
        a0.x = fmaf(v.x, w, a0.x); a0.y = fmaf(v.y, w, a0.y);
        a0.z = fmaf(v.z, w, a0.z); a0.w = fmaf(v.w, w, a0.w);
    }

    a0.x = fmaxf(a0.x + a1.x, 0.f);
    a0.y = fmaxf(a0.y + a1.y, 0.f);
    a0.z = fmaxf(a0.z + a1.z, 0.f);
    a0.w = fmaxf(a0.w + a1.w, 0.f);
    ((float4*)(out + (size_t)i * 128))[lane] = a0;
}

// ---------------- launch ----------------

extern "C" void kernel_launch(void* const* d_in, const int* in_sizes, int n_in,
                              void* d_out, int out_size, void* d_ws, size_t ws_size,
                              hipStream_t stream) {
    const float* x = (const float*)d_in[0];
    const int* ei = (const int*)d_in[1];
    const int E = in_sizes[1] / 2;
    const int* srcI = ei;
    const int* dstI = ei + E;
    const float* W[4] = {(const float*)d_in[2], (const float*)d_in[4],
                         (const float*)d_in[6], (const float*)d_in[8]};
    const float* b[4] = {(const float*)d_in[3], (const float*)d_in[5],
                         (const float*)d_in[7], (const float*)d_in[9]};
    const int N = in_sizes[0] / 128;

    // ws layout (4B units); cnt+cursor adjacent for one memset
    int* iws = (int*)d_ws;
    int* cnt = iws;                           // [0, 50176)
    int* cursor = iws + 50176;                // [50176, 100352)
    int* rowptr = iws + 100352;               // [100352, 150528)
    float* dinv = (float*)(iws + 150528);     // [150528, 200704)
    int* bsum = iws + 200704;                 // 64
    int* boffs = iws + 200768;                // 64
    int2* edata = (int2*)(iws + 200832);      // 2*E ints
    float* bufA = (float*)(iws + 200832 + 2 * E);
    float* bufB = bufA + (size_t)N * 128;

    dim3 blk(256);
    int gE = (E + 255) / 256;
    int NB = (N + 1023) / 1024;
    int gGemm = (N + 63) / 64;
    int gGather = (N * 32 + 255) / 256;

    hipMemsetAsync(iws, 0, (size_t)100352 * 4, stream);  // cnt + cursor
    hist_k<<<gE, blk, 0, stream>>>(dstI, cnt, E);
    bsum_k<<<NB, blk, 0, stream>>>(cnt, bsum, dinv, N);
    bscan_k<<<1, blk, 0, stream>>>(bsum, boffs, NB);
    rowscan_k<<<NB, blk, 0, stream>>>(cnt, boffs, rowptr, N);
    fill_k<<<gE, blk, 0, stream>>>(srcI, dstI, dinv, rowptr, cursor, edata, E);

    const float* in = x;
    for (int l = 0; l < 4; ++l) {
        gemm_k<<<gGemm, blk, 0, stream>>>(in, W[l], bufA, N);
        float* agg = (l == 3) ? (float*)d_out : bufB;
        gather_agg_k<<<gGather, blk, 0, stream>>>(bufA, rowptr, edata, dinv, b[l], agg, N);
        in = agg;
    }
}

// Round 5
// 335.082 us; speedup vs baseline: 17.3285x; 1.3105x over previous
//
#include <hip/hip_runtime.h>
#include <hip/hip_fp16.h>

// ---------------- setup kernels (once per call) ----------------

__global__ void hist_k(const int* __restrict__ dst, int* __restrict__ cnt, int E) {
    int e = blockIdx.x * 256 + threadIdx.x;
    if (e < E) atomicAdd(&cnt[dst[e]], 1);
}

// per-block sums of cnt (1024/block) + fused dinv = rsqrt(cnt+1)
__global__ void bsum_k(const int* __restrict__ cnt, int* __restrict__ bsum,
                       float* __restrict__ dinv, int n) {
    int b = blockIdx.x, tid = threadIdx.x;
    int base = b * 1024 + tid * 4;
    int4 v = make_int4(0, 0, 0, 0);
    if (base + 3 < n) v = *(const int4*)(cnt + base);
    else {
        if (base + 0 < n) v.x = cnt[base + 0];
        if (base + 1 < n) v.y = cnt[base + 1];
        if (base + 2 < n) v.z = cnt[base + 2];
    }
    if (base + 3 < n) {
        float4 dv;
        dv.x = rsqrtf((float)v.x + 1.0f);
        dv.y = rsqrtf((float)v.y + 1.0f);
        dv.z = rsqrtf((float)v.z + 1.0f);
        dv.w = rsqrtf((float)v.w + 1.0f);
        *(float4*)(dinv + base) = dv;
    } else {
        if (base + 0 < n) dinv[base + 0] = rsqrtf((float)v.x + 1.0f);
        if (base + 1 < n) dinv[base + 1] = rsqrtf((float)v.y + 1.0f);
        if (base + 2 < n) dinv[base + 2] = rsqrtf((float)v.z + 1.0f);
    }
    int s = v.x + v.y + v.z + v.w;
#pragma unroll
    for (int off = 32; off; off >>= 1) s += __shfl_xor(s, off, 64);
    __shared__ int wsh[4];
    if ((tid & 63) == 0) wsh[tid >> 6] = s;
    __syncthreads();
    if (tid == 0) bsum[b] = wsh[0] + wsh[1] + wsh[2] + wsh[3];
}

__global__ void bscan_k(const int* __restrict__ bsum, int* __restrict__ boffs, int nb) {
    int tid = threadIdx.x;
    int lane = tid & 63, wid = tid >> 6;
    int s = (tid < nb) ? bsum[tid] : 0;
    int incl = s;
#pragma unroll
    for (int off = 1; off < 64; off <<= 1) {
        int t = __shfl_up(incl, off, 64);
        if (lane >= off) incl += t;
    }
    __shared__ int wsh[4];
    if (lane == 63) wsh[wid] = incl;
    __syncthreads();
    int woff = 0;
    for (int w = 0; w < wid; ++w) woff += wsh[w];
    if (tid < nb) boffs[tid] = woff + incl - s;  // exclusive
}

__global__ void rowscan_k(const int* __restrict__ cnt, const int* __restrict__ boffs,
                          int* __restrict__ rowptr, int n) {
    int b = blockIdx.x, tid = threadIdx.x;
    int lane = tid & 63, wid = tid >> 6;
    int base = b * 1024 + tid * 4;
    int4 v = make_int4(0, 0, 0, 0);
    if (base + 3 < n) v = *(const int4*)(cnt + base);
    else {
        if (base + 0 < n) v.x = cnt[base + 0];
        if (base + 1 < n) v.y = cnt[base + 1];
        if (base + 2 < n) v.z = cnt[base + 2];
    }
    int s = v.x + v.y + v.z + v.w;
    int incl = s;
#pragma unroll
    for (int off = 1; off < 64; off <<= 1) {
        int t = __shfl_up(incl, off, 64);
        if (lane >= off) incl += t;
    }
    __shared__ int wsh[4];
    if (lane == 63) wsh[wid] = incl;
    __syncthreads();
    int woff = boffs[b];
    for (int w = 0; w < wid; ++w) woff += wsh[w];
    int e0 = woff + incl - s;
    int o0 = e0 + v.x, o1 = o0 + v.y, o2 = o1 + v.z, o3 = o2 + v.w;
    if (base + 0 < n) rowptr[base + 1] = o0;
    if (base + 1 < n) rowptr[base + 2] = o1;
    if (base + 2 < n) rowptr[base + 3] = o2;
    if (base + 3 < n) rowptr[base + 4] = o3;
    if (b == 0 && tid == 0) rowptr[0] = 0;
}

// edata[pos] = (src << 16) | fp16(weight)   (N < 65536 so src fits 16 bits)
__global__ void fill_k(const int* __restrict__ src, const int* __restrict__ dst,
                       const float* __restrict__ dinv, const int* __restrict__ rowptr,
                       int* __restrict__ cursor, unsigned int* __restrict__ edata, int E) {
    int e = blockIdx.x * 256 + threadIdx.x;
    if (e >= E) return;
    int d = dst[e];
    int s = src[e];
    int pos = rowptr[d] + atomicAdd(&cursor[d], 1);
    float w = dinv[s] * dinv[d];
    unsigned short wh = __half_as_ushort(__float2half(w));
    edata[pos] = ((unsigned int)s << 16) | (unsigned int)wh;
}

// ---------------- per-layer kernels ----------------

// H = X @ W (fp32 accum), output stored as fp16 rows (256 B/row).
// 64 X-rows staged in 32KB LDS; W read from global (L2-hot), 1-quad pipeline.
__global__ __launch_bounds__(256, 4) void gemm_k(const float* __restrict__ X,
                                                 const float* __restrict__ W,
                                                 __half* __restrict__ Hh, int N) {
    __shared__ float4 xs[64 * 32];  // 32 KB
    int tid = threadIdx.x;
    int row0 = blockIdx.x * 64;
    int nrows = min(64, N - row0);
    const float4* X4 = (const float4*)X;
#pragma unroll
    for (int i = 0; i < 8; ++i) {
        int idx = i * 256 + tid;
        int r = idx >> 5;
        xs[idx] = (r < nrows) ? X4[(size_t)row0 * 32 + idx] : make_float4(0.f, 0.f, 0.f, 0.f);
    }
    __syncthreads();

    int c4 = tid & 31;
    int rg = tid >> 5;
    float acc[8][4] = {};
    const float4* W4 = (const float4*)W;

    float4 w[4];
#pragma unroll
    for (int j = 0; j < 4; ++j) w[j] = W4[j * 32 + c4];

    for (int kk = 0; kk < 32; ++kk) {
        float4 wn[4];
        int kn = (kk + 1) & 31;
#pragma unroll
        for (int j = 0; j < 4; ++j) wn[j] = W4[(kn * 4 + j) * 32 + c4];
#pragma unroll
        for (int rr = 0; rr < 8; ++rr) {
            float4 xv = xs[(rg + 8 * rr) * 32 + kk];
#pragma unroll
            for (int c = 0; c < 4; ++c) {
                float* a = &acc[rr][c];
                *a = fmaf(xv.x, (&w[0].x)[c], *a);
                *a = fmaf(xv.y, (&w[1].x)[c], *a);
                *a = fmaf(xv.z, (&w[2].x)[c], *a);
                *a = fmaf(xv.w, (&w[3].x)[c], *a);
            }
        }
#pragma unroll
        for (int j = 0; j < 4; ++j) w[j] = wn[j];
    }

#pragma unroll
    for (int rr = 0; rr < 8; ++rr) {
        int r = rg + 8 * rr;
        if (r < nrows) {
            __half2 h0 = __floats2half2_rn(acc[rr][0], acc[rr][1]);
            __half2 h1 = __floats2half2_rn(acc[rr][2], acc[rr][3]);
            uint2 pk;
            pk.x = *(unsigned int*)&h0;
            pk.y = *(unsigned int*)&h1;
            ((uint2*)(Hh + (size_t)(row0 + r) * 128))[c4] = pk;
        }
    }
}

__device__ __forceinline__ void acc8(float* a, uint4 v, float w) {
    unsigned int u[4] = {v.x, v.y, v.z, v.w};
#pragma unroll
    for (int j = 0; j < 4; ++j) {
        __half2 h = *(__half2*)&u[j];
        float2 f = __half22float2(h);
        a[2 * j + 0] = fmaf(f.x, w, a[2 * j + 0]);
        a[2 * j + 1] = fmaf(f.y, w, a[2 * j + 1]);
    }
}

// out[i] = relu(b + dinv[i]^2 * H[i] + sum_{e: dst=i} w_e * H[src_e])
// 16 lanes/node, 8 features/lane (uint4 = 8 halves), 4 edges in flight.
__global__ __launch_bounds__(256) void gather_agg_k(
        const __half* __restrict__ Hh, const int* __restrict__ rowptr,
        const unsigned int* __restrict__ edata, const float* __restrict__ dinv,
        const float* __restrict__ b, float* __restrict__ out, int N) {
    int t = blockIdx.x * 256 + threadIdx.x;
    int i = t >> 4;
    if (i >= N) return;
    int lane = t & 15;
    const uint4* H4 = (const uint4*)Hh;  // row = 16 uint4

    float dn = dinv[i];
    float sn = dn * dn;

    float a[8] = {};
    uint4 hi = H4[(size_t)i * 16 + lane];
    acc8(a, hi, sn);

    int p0 = rowptr[i];
    int p1 = rowptr[i + 1];
    int p = p0;
    for (; p + 4 <= p1; p += 4) {
        unsigned int e0 = edata[p + 0];
        unsigned int e1 = edata[p + 1];
        unsigned int e2 = edata[p + 2];
        unsigned int e3 = edata[p + 3];
        uint4 v0 = H4[(size_t)(e0 >> 16) * 16 + lane];
        uint4 v1 = H4[(size_t)(e1 >> 16) * 16 + lane];
        uint4 v2 = H4[(size_t)(e2 >> 16) * 16 + lane];
        uint4 v3 = H4[(size_t)(e3 >> 16) * 16 + lane];
        float w0 = __half2float(__ushort_as_half((unsigned short)(e0 & 0xffffu)));
        float w1 = __half2float(__ushort_as_half((unsigned short)(e1 & 0xffffu)));
        float w2 = __half2float(__ushort_as_half((unsigned short)(e2 & 0xffffu)));
        float w3 = __half2float(__ushort_as_half((unsigned short)(e3 & 0xffffu)));
        acc8(a, v0, w0);
        acc8(a, v1, w1);
        acc8(a, v2, w2);
        acc8(a, v3, w3);
    }
    for (; p < p1; ++p) {
        unsigned int e = edata[p];
        uint4 v = H4[(size_t)(e >> 16) * 16 + lane];
        float w = __half2float(__ushort_as_half((unsigned short)(e & 0xffffu)));
        acc8(a, v, w);
    }

    const float4* b4 = (const float4*)b;
    float4 bb0 = b4[lane * 2 + 0];
    float4 bb1 = b4[lane * 2 + 1];
    float4 o0, o1;
    o0.x = fmaxf(a[0] + bb0.x, 0.f);
    o0.y = fmaxf(a[1] + bb0.y, 0.f);
    o0.z = fmaxf(a[2] + bb0.z, 0.f);
    o0.w = fmaxf(a[3] + bb0.w, 0.f);
    o1.x = fmaxf(a[4] + bb1.x, 0.f);
    o1.y = fmaxf(a[5] + bb1.y, 0.f);
    o1.z = fmaxf(a[6] + bb1.z, 0.f);
    o1.w = fmaxf(a[7] + bb1.w, 0.f);
    float4* orow = (float4*)(out + (size_t)i * 128);
    orow[lane * 2 + 0] = o0;
    orow[lane * 2 + 1] = o1;
}

// ---------------- launch ----------------

extern "C" void kernel_launch(void* const* d_in, const int* in_sizes, int n_in,
                              void* d_out, int out_size, void* d_ws, size_t ws_size,
                              hipStream_t stream) {
    const float* x = (const float*)d_in[0];
    const int* ei = (const int*)d_in[1];
    const int E = in_sizes[1] / 2;
    const int* srcI = ei;
    const int* dstI = ei + E;
    const float* W[4] = {(const float*)d_in[2], (const float*)d_in[4],
                         (const float*)d_in[6], (const float*)d_in[8]};
    const float* b[4] = {(const float*)d_in[3], (const float*)d_in[5],
                         (const float*)d_in[7], (const float*)d_in[9]};
    const int N = in_sizes[0] / 128;

    // ws layout (4B units); cnt+cursor adjacent for one memset
    int* iws = (int*)d_ws;
    int* cnt = iws;                              // [0, 50176)
    int* cursor = iws + 50176;                   // [50176, 100352)
    int* rowptr = iws + 100352;                  // [100352, 150528)
    float* dinv = (float*)(iws + 150528);        // [150528, 200704)
    int* bsum = iws + 200704;                    // 64
    int* boffs = iws + 200768;                   // 64
    unsigned int* edata = (unsigned int*)(iws + 200832);  // E uints
    int edEnd = 200832 + ((E + 3) & ~3);
    __half* Hh = (__half*)(iws + edEnd);         // N*128 halves = N*64 ints
    float* bufB = (float*)(iws + edEnd + (size_t)N * 64);  // N*128 floats

    dim3 blk(256);
    int gE = (E + 255) / 256;
    int NB = (N + 1023) / 1024;
    int gGemm = (N + 63) / 64;
    int gGather = (N * 16 + 255) / 256;

    hipMemsetAsync(iws, 0, (size_t)100352 * 4, stream);  // cnt + cursor
    hist_k<<<gE, blk, 0, stream>>>(dstI, cnt, E);
    bsum_k<<<NB, blk, 0, stream>>>(cnt, bsum, dinv, N);
    bscan_k<<<1, blk, 0, stream>>>(bsum, boffs, NB);
    rowscan_k<<<NB, blk, 0, stream>>>(cnt, boffs, rowptr, N);
    fill_k<<<gE, blk, 0, stream>>>(srcI, dstI, dinv, rowptr, cursor, edata, E);

    const float* in = x;
    for (int l = 0; l < 4; ++l) {
        gemm_k<<<gGemm, blk, 0, stream>>>(in, W[l], Hh, N);
        float* agg = (l == 3) ? (float*)d_out : bufB;
        gather_agg_k<<<gGather, blk, 0, stream>>>(Hh, rowptr, edata, dinv, b[l], agg, N);
        in = agg;
    }
}

// Round 6
// 272.820 us; speedup vs baseline: 21.2832x; 1.2282x over previous
//
#include <hip/hip_runtime.h>
#include <hip/hip_fp16.h>

typedef __attribute__((ext_vector_type(8))) _Float16 half8;
typedef __attribute__((ext_vector_type(4))) float f32x4;

static __device__ __forceinline__ half8 as_half8(uint4 u) {
    union { uint4 u; half8 h; } c; c.u = u; return c.h;
}

// ---------------- setup kernels (once per call) ----------------

// zero cnt (50176 ints) + cast x -> fp16 Xh
__global__ void prep_k(int* __restrict__ cnt, const float* __restrict__ x,
                       __half* __restrict__ Xh, int N) {
    int stride = gridDim.x * 256;
    int tid = blockIdx.x * 256 + threadIdx.x;
    for (int i = tid; i < 12544; i += stride) ((int4*)cnt)[i] = make_int4(0, 0, 0, 0);
    int nOut = N * 16;  // uint4 = 8 halves
    const float4* x4 = (const float4*)x;
    uint4* o4 = (uint4*)Xh;
    for (int i = tid; i < nOut; i += stride) {
        float4 f0 = x4[i * 2 + 0];
        float4 f1 = x4[i * 2 + 1];
        __half2 h0 = __floats2half2_rn(f0.x, f0.y);
        __half2 h1 = __floats2half2_rn(f0.z, f0.w);
        __half2 h2 = __floats2half2_rn(f1.x, f1.y);
        __half2 h3 = __floats2half2_rn(f1.z, f1.w);
        uint4 o;
        o.x = *(unsigned int*)&h0;
        o.y = *(unsigned int*)&h1;
        o.z = *(unsigned int*)&h2;
        o.w = *(unsigned int*)&h3;
        o4[i] = o;
    }
}

__global__ void hist_k(const int* __restrict__ dst, int* __restrict__ cnt, int E) {
    int e4 = blockIdx.x * 256 + threadIdx.x;
    int nE4 = E >> 2;
    if (e4 < nE4) {
        int4 d = ((const int4*)dst)[e4];
        atomicAdd(&cnt[d.x], 1);
        atomicAdd(&cnt[d.y], 1);
        atomicAdd(&cnt[d.z], 1);
        atomicAdd(&cnt[d.w], 1);
    } else if (e4 == nE4) {
        for (int e = nE4 * 4; e < E; ++e) atomicAdd(&cnt[dst[e]], 1);
    }
}

// per-block sums of cnt (1024/block) + fused dinv = rsqrt(cnt+1)
__global__ void bsum_k(const int* __restrict__ cnt, int* __restrict__ bsum,
                       float* __restrict__ dinv, int n) {
    int b = blockIdx.x, tid = threadIdx.x;
    int base = b * 1024 + tid * 4;
    int4 v = make_int4(0, 0, 0, 0);
    if (base + 3 < n) v = *(const int4*)(cnt + base);
    else {
        if (base + 0 < n) v.x = cnt[base + 0];
        if (base + 1 < n) v.y = cnt[base + 1];
        if (base + 2 < n) v.z = cnt[base + 2];
    }
    if (base + 3 < n) {
        float4 dv;
        dv.x = rsqrtf((float)v.x + 1.0f);
        dv.y = rsqrtf((float)v.y + 1.0f);
        dv.z = rsqrtf((float)v.z + 1.0f);
        dv.w = rsqrtf((float)v.w + 1.0f);
        *(float4*)(dinv + base) = dv;
    } else {
        if (base + 0 < n) dinv[base + 0] = rsqrtf((float)v.x + 1.0f);
        if (base + 1 < n) dinv[base + 1] = rsqrtf((float)v.y + 1.0f);
        if (base + 2 < n) dinv[base + 2] = rsqrtf((float)v.z + 1.0f);
    }
    int s = v.x + v.y + v.z + v.w;
#pragma unroll
    for (int off = 32; off; off >>= 1) s += __shfl_xor(s, off, 64);
    __shared__ int wsh[4];
    if ((tid & 63) == 0) wsh[tid >> 6] = s;
    __syncthreads();
    if (tid == 0) bsum[b] = wsh[0] + wsh[1] + wsh[2] + wsh[3];
}

__global__ void bscan_k(const int* __restrict__ bsum, int* __restrict__ boffs, int nb) {
    int tid = threadIdx.x;
    int lane = tid & 63, wid = tid >> 6;
    int s = (tid < nb) ? bsum[tid] : 0;
    int incl = s;
#pragma unroll
    for (int off = 1; off < 64; off <<= 1) {
        int t = __shfl_up(incl, off, 64);
        if (lane >= off) incl += t;
    }
    __shared__ int wsh[4];
    if (lane == 63) wsh[wid] = incl;
    __syncthreads();
    int woff = 0;
    for (int w = 0; w < wid; ++w) woff += wsh[w];
    if (tid < nb) boffs[tid] = woff + incl - s;  // exclusive
}

__global__ void rowscan_k(const int* __restrict__ cnt, const int* __restrict__ boffs,
                          int* __restrict__ rowptr, int n) {
    int b = blockIdx.x, tid = threadIdx.x;
    int lane = tid & 63, wid = tid >> 6;
    int base = b * 1024 + tid * 4;
    int4 v = make_int4(0, 0, 0, 0);
    if (base + 3 < n) v = *(const int4*)(cnt + base);
    else {
        if (base + 0 < n) v.x = cnt[base + 0];
        if (base + 1 < n) v.y = cnt[base + 1];
        if (base + 2 < n) v.z = cnt[base + 2];
    }
    int s = v.x + v.y + v.z + v.w;
    int incl = s;
#pragma unroll
    for (int off = 1; off < 64; off <<= 1) {
        int t = __shfl_up(incl, off, 64);
        if (lane >= off) incl += t;
    }
    __shared__ int wsh[4];
    if (lane == 63) wsh[wid] = incl;
    __syncthreads();
    int woff = boffs[b];
    for (int w = 0; w < wid; ++w) woff += wsh[w];
    int e0 = woff + incl - s;
    int o0 = e0 + v.x, o1 = o0 + v.y, o2 = o1 + v.z, o3 = o2 + v.w;
    if (base + 0 < n) rowptr[base + 1] = o0;
    if (base + 1 < n) rowptr[base + 2] = o1;
    if (base + 2 < n) rowptr[base + 3] = o2;
    if (base + 3 < n) rowptr[base + 4] = o3;
    if (b == 0 && tid == 0) rowptr[0] = 0;
}

// cursor = rowptr[0..n)
__global__ void copy_k(const int* __restrict__ rowptr, int* __restrict__ cursor, int n4) {
    int i = blockIdx.x * 256 + threadIdx.x;
    if (i < n4) ((int4*)cursor)[i] = ((const int4*)rowptr)[i];
}

// edata[pos] = (src << 16) | fp16(weight)
__global__ void fill_k(const int* __restrict__ src, const int* __restrict__ dst,
                       const float* __restrict__ dinv,
                       int* __restrict__ cursor, unsigned int* __restrict__ edata, int E) {
    int e4 = blockIdx.x * 256 + threadIdx.x;
    int nE4 = E >> 2;
    if (e4 < nE4) {
        int4 d = ((const int4*)dst)[e4];
        int4 s = ((const int4*)src)[e4];
        int ds[4] = {d.x, d.y, d.z, d.w};
        int ss[4] = {s.x, s.y, s.z, s.w};
#pragma unroll
        for (int j = 0; j < 4; ++j) {
            int pos = atomicAdd(&cursor[ds[j]], 1);
            float w = dinv[ss[j]] * dinv[ds[j]];
            unsigned short wh = __half_as_ushort(__float2half(w));
            edata[pos] = ((unsigned int)ss[j] << 16) | (unsigned int)wh;
        }
    } else if (e4 == nE4) {
        for (int e = nE4 * 4; e < E; ++e) {
            int d = dst[e], s = src[e];
            int pos = atomicAdd(&cursor[d], 1);
            float w = dinv[s] * dinv[d];
            unsigned short wh = __half_as_ushort(__float2half(w));
            edata[pos] = ((unsigned int)s << 16) | (unsigned int)wh;
        }
    }
}

// Pre-shuffle all 4 W matrices (fp32 [128][128]) into MFMA B-fragment order, fp16.
// Fragment (ks, ct, lane) holds B[k][col], k = ks*32 + (lane>>4)*8 + j, col = ct*16 + (lane&15).
// Wshuf layout: layer*2048 + (ks*8 + ct)*64 + lane  (uint4 units)
__global__ void wshuf_k(const float* __restrict__ W0, const float* __restrict__ W1,
                        const float* __restrict__ W2, const float* __restrict__ W3,
                        uint4* __restrict__ Wshuf) {
    int gid = blockIdx.x * 256 + threadIdx.x;  // [0, 8192)
    int layer = gid >> 11;
    int tid2 = gid & 2047;
    int ks = tid2 >> 9;
    int rem = tid2 & 511;
    int ct = rem >> 6;
    int lane = rem & 63;
    const float* W = (layer == 0) ? W0 : (layer == 1) ? W1 : (layer == 2) ? W2 : W3;
    int col = ct * 16 + (lane & 15);
    int k0 = ks * 32 + (lane >> 4) * 8;
    __half h[8];
#pragma unroll
    for (int j = 0; j < 8; ++j) h[j] = __float2half(W[(k0 + j) * 128 + col]);
    uint4 o;
    o.x = *(unsigned int*)&h[0];
    o.y = *(unsigned int*)&h[2];
    o.z = *(unsigned int*)&h[4];
    o.w = *(unsigned int*)&h[6];
    Wshuf[gid] = o;
}

// ---------------- per-layer kernels ----------------

// H = X @ W via v_mfma_f32_16x16x32_f16.
// 256 threads = 4 waves; wave handles 64 rows (4 row-tiles of 16); block = 256 rows.
// Wshuf (one layer, 2048 uint4 = 32KB) staged in LDS.
__global__ __launch_bounds__(256) void gemm_k(const __half* __restrict__ Xh,
                                              const uint4* __restrict__ Wsh,
                                              __half* __restrict__ Hh, int N) {
    __shared__ uint4 bsh[2048];  // 32 KB
    int tid = threadIdx.x;
#pragma unroll
    for (int i = 0; i < 8; ++i) bsh[i * 256 + tid] = Wsh[i * 256 + tid];
    __syncthreads();

    int lane = tid & 63;
    int wv = tid >> 6;
    int rbase = blockIdx.x * 256 + wv * 64;
    int lr = lane & 15;       // A row within tile / D col within tile
    int lk = lane >> 4;       // k-chunk selector

    const uint4* X4 = (const uint4*)Xh;  // row = 16 uint4

    f32x4 acc[4][8];
#pragma unroll
    for (int rt = 0; rt < 4; ++rt)
#pragma unroll
        for (int ct = 0; ct < 8; ++ct) acc[rt][ct] = (f32x4){0.f, 0.f, 0.f, 0.f};

#pragma unroll
    for (int ks = 0; ks < 4; ++ks) {
        half8 a[4];
#pragma unroll
        for (int rt = 0; rt < 4; ++rt) {
            int row = rbase + rt * 16 + lr;
            uint4 u = (row < N) ? X4[(size_t)row * 16 + ks * 4 + lk]
                                : make_uint4(0, 0, 0, 0);
            a[rt] = as_half8(u);
        }
#pragma unroll
        for (int ct = 0; ct < 8; ++ct) {
            half8 b = as_half8(bsh[(ks * 8 + ct) * 64 + lane]);
#pragma unroll
            for (int rt = 0; rt < 4; ++rt) {
                acc[rt][ct] = __builtin_amdgcn_mfma_f32_16x16x32_f16(a[rt], b, acc[rt][ct], 0, 0, 0);
            }
        }
    }

    // D: col = lane&15 (lr), row = (lane>>4)*4 + r
#pragma unroll
    for (int rt = 0; rt < 4; ++rt) {
        int row0 = rbase + rt * 16 + lk * 4;
#pragma unroll
        for (int ct = 0; ct < 8; ++ct) {
            int col = ct * 16 + lr;
            f32x4 v = acc[rt][ct];
#pragma unroll
            for (int r = 0; r < 4; ++r) {
                int row = row0 + r;
                if (row < N) Hh[(size_t)row * 128 + col] = __float2half(v[r]);
            }
        }
    }
}

__device__ __forceinline__ void acc8(float* a, uint4 v, float w) {
    unsigned int u[4] = {v.x, v.y, v.z, v.w};
#pragma unroll
    for (int j = 0; j < 4; ++j) {
        __half2 h = *(__half2*)&u[j];
        float2 f = __half22float2(h);
        a[2 * j + 0] = fmaf(f.x, w, a[2 * j + 0]);
        a[2 * j + 1] = fmaf(f.y, w, a[2 * j + 1]);
    }
}

// out[i] = relu(b + dinv[i]^2 * H[i] + sum_{e: dst=i} w_e * H[src_e])
// 16 lanes/node, 8 features/lane, 4 edges in flight. F16OUT: write fp16, else fp32.
template <bool F16OUT>
__global__ __launch_bounds__(256) void gather_agg_k(
        const __half* __restrict__ Hh, const int* __restrict__ rowptr,
        const unsigned int* __restrict__ edata, const float* __restrict__ dinv,
        const float* __restrict__ b, void* __restrict__ out, int N) {
    int t = blockIdx.x * 256 + threadIdx.x;
    int i = t >> 4;
    if (i >= N) return;
    int lane = t & 15;
    const uint4* H4 = (const uint4*)Hh;  // row = 16 uint4

    float dn = dinv[i];
    float sn = dn * dn;

    float a[8] = {};
    uint4 hi = H4[(size_t)i * 16 + lane];
    acc8(a, hi, sn);

    int p0 = rowptr[i];
    int p1 = rowptr[i + 1];
    int p = p0;
    for (; p + 4 <= p1; p += 4) {
        unsigned int e0 = edata[p + 0];
        unsigned int e1 = edata[p + 1];
        unsigned int e2 = edata[p + 2];
        unsigned int e3 = edata[p + 3];
        uint4 v0 = H4[(size_t)(e0 >> 16) * 16 + lane];
        uint4 v1 = H4[(size_t)(e1 >> 16) * 16 + lane];
        uint4 v2 = H4[(size_t)(e2 >> 16) * 16 + lane];
        uint4 v3 = H4[(size_t)(e3 >> 16) * 16 + lane];
        float w0 = __half2float(__ushort_as_half((unsigned short)(e0 & 0xffffu)));
        float w1 = __half2float(__ushort_as_half((unsigned short)(e1 & 0xffffu)));
        float w2 = __half2float(__ushort_as_half((unsigned short)(e2 & 0xffffu)));
        float w3 = __half2float(__ushort_as_half((unsigned short)(e3 & 0xffffu)));
        acc8(a, v0, w0);
        acc8(a, v1, w1);
        acc8(a, v2, w2);
        acc8(a, v3, w3);
    }
    for (; p < p1; ++p) {
        unsigned int e = edata[p];
        uint4 v = H4[(size_t)(e >> 16) * 16 + lane];
        float w = __half2float(__ushort_as_half((unsigned short)(e & 0xffffu)));
        acc8(a, v, w);
    }

    const float4* b4 = (const float4*)b;
    float4 bb0 = b4[lane * 2 + 0];
    float4 bb1 = b4[lane * 2 + 1];
    float r[8];
    r[0] = fmaxf(a[0] + bb0.x, 0.f);
    r[1] = fmaxf(a[1] + bb0.y, 0.f);
    r[2] = fmaxf(a[2] + bb0.z, 0.f);
    r[3] = fmaxf(a[3] + bb0.w, 0.f);
    r[4] = fmaxf(a[4] + bb1.x, 0.f);
    r[5] = fmaxf(a[5] + bb1.y, 0.f);
    r[6] = fmaxf(a[6] + bb1.z, 0.f);
    r[7] = fmaxf(a[7] + bb1.w, 0.f);

    if (F16OUT) {
        __half2 h0 = __floats2half2_rn(r[0], r[1]);
        __half2 h1 = __floats2half2_rn(r[2], r[3]);
        __half2 h2 = __floats2half2_rn(r[4], r[5]);
        __half2 h3 = __floats2half2_rn(r[6], r[7]);
        uint4 o;
        o.x = *(unsigned int*)&h0;
        o.y = *(unsigned int*)&h1;
        o.z = *(unsigned int*)&h2;
        o.w = *(unsigned int*)&h3;
        ((uint4*)out)[(size_t)i * 16 + lane] = o;
    } else {
        float4* orow = (float4*)((float*)out + (size_t)i * 128);
        orow[lane * 2 + 0] = make_float4(r[0], r[1], r[2], r[3]);
        orow[lane * 2 + 1] = make_float4(r[4], r[5], r[6], r[7]);
    }
}

// ---------------- launch ----------------

extern "C" void kernel_launch(void* const* d_in, const int* in_sizes, int n_in,
                              void* d_out, int out_size, void* d_ws, size_t ws_size,
                              hipStream_t stream) {
    const float* x = (const float*)d_in[0];
    const int* ei = (const int*)d_in[1];
    const int E = in_sizes[1] / 2;
    const int* srcI = ei;
    const int* dstI = ei + E;
    const float* b[4] = {(const float*)d_in[3], (const float*)d_in[5],
                         (const float*)d_in[7], (const float*)d_in[9]};
    const int N = in_sizes[0] / 128;

    // ws layout (4B units)
    int* iws = (int*)d_ws;
    int* cnt = iws;                              // [0, 50176)
    int* cursor = iws + 50176;                   // [50176, 100352)
    int* rowptr = iws + 100352;                  // [100352, 150528)
    float* dinv = (float*)(iws + 150528);        // [150528, 200704)
    int* bsum = iws + 200704;                    // 64
    int* boffs = iws + 200768;                   // 64
    unsigned int* edata = (unsigned int*)(iws + 200832);    // E uints
    int edEnd = 200832 + ((E + 3) & ~3);
    uint4* Wshuf = (uint4*)(iws + edEnd);        // 8192 uint4 = 32768 ints
    int wsEnd = edEnd + 32768;
    __half* Xh = (__half*)(iws + wsEnd);         // N*128 halves = N*64 ints
    __half* Hh = (__half*)(iws + wsEnd + (size_t)N * 64);

    dim3 blk(256);
    int gE4 = ((E >> 2) + 1 + 255) / 256;
    int NB = (N + 1023) / 1024;
    int gCopy = ((N + 3) / 4 + 255) / 256;
    int gGemm = (N + 255) / 256;
    int gGather = (N * 16 + 255) / 256;

    prep_k<<<1024, blk, 0, stream>>>(cnt, x, Xh, N);
    hist_k<<<gE4, blk, 0, stream>>>(dstI, cnt, E);
    bsum_k<<<NB, blk, 0, stream>>>(cnt, bsum, dinv, N);
    bscan_k<<<1, blk, 0, stream>>>(bsum, boffs, NB);
    rowscan_k<<<NB, blk, 0, stream>>>(cnt, boffs, rowptr, N);
    copy_k<<<gCopy, blk, 0, stream>>>(rowptr, cursor, (N + 3) / 4);
    fill_k<<<gE4, blk, 0, stream>>>(srcI, dstI, dinv, cursor, edata, E);
    wshuf_k<<<32, blk, 0, stream>>>((const float*)d_in[2], (const float*)d_in[4],
                                    (const float*)d_in[6], (const float*)d_in[8], Wshuf);

    const __half* in = Xh;
    for (int l = 0; l < 4; ++l) {
        gemm_k<<<gGemm, blk, 0, stream>>>(in, Wshuf + l * 2048, Hh, N);
        if (l == 3) {
            gather_agg_k<false><<<gGather, blk, 0, stream>>>(Hh, rowptr, edata, dinv, b[l], d_out, N);
        } else {
            gather_agg_k<true><<<gGather, blk, 0, stream>>>(Hh, rowptr, edata, dinv, b[l], Xh, N);
            in = Xh;
        }
    }
}